// Round 9
// baseline (195.075 us; speedup 1.0000x reference)
//
#include <hip/hip_runtime.h>
#include <hip/hip_bf16.h>
#include <cstdint>
#include <cstddef>

// B=4, S=2048, D=768 single-head causal attention, fp32 I/O.
// Round 14: scores+V^T moved off the 8-phase 256^2 core (62 us @ 1 block/CU,
// MfmaUtil 14) onto the PROVEN BK=64 double-buffered 2-phase core (gemm64:
// one __syncthreads+drain per 64 K-elements, prefetch in flight across the
// compute phase) that measured ~570-611 TF at >=3 blocks/CU (qkv-R0, pv-R8).
// One 1856-block dispatch of 64x128 tiles: 1088 compact-causal score tiles
// (R5-baseline analytic decode + exp/mask/rowsum epilogue, verbatim) + 768
// V^T tiles. All blocks K=768 uniform -> XCD swizzle safe. 48 KB LDS -> 3
// blocks/CU. 8-phase core deleted. qk (BK=32 2-phase, 768 blocks), pv
// (gemm64, 768 blocks LPT), cvt unchanged from R8 (174.7 us best).

typedef __attribute__((ext_vector_type(8))) short short8;   // 8 x bf16
typedef __attribute__((ext_vector_type(4))) float f32x4;    // MFMA C/D

#define GPTR(p) (const __attribute__((address_space(1))) void*)(p)
#define LPTR(p) (__attribute__((address_space(3))) void*)(p)

constexpr int CB = 4, CS = 2048, CD = 768;
constexpr int CBS = CB * CS;            // 8192

// T1: XCD-aware bijective swizzle (requires nwg % 8 == 0). Only for grids
// with uniform block durations (R7 lesson: never on LPT grids).
__device__ __forceinline__ int xcd_swz(int bid, int nwg) {
    return (bid & 7) * (nwg >> 3) + (bid >> 3);
}

__device__ inline unsigned short f2bf_bits(float v) {
    __hip_bfloat16 h = __float2bfloat16(v);
    unsigned short u;
    __builtin_memcpy(&u, &h, 2);
    return u;
}

__device__ inline ushort4 cvt4(float4 f) {
    ushort4 u;
    u.x = f2bf_bits(f.x); u.y = f2bf_bits(f.y);
    u.z = f2bf_bits(f.z); u.w = f2bf_bits(f.w);
    return u;
}

template <int MI>
__device__ __forceinline__ void zero_acc(f32x4 (&acc)[MI][4]) {
#pragma unroll
    for (int i = 0; i < MI; ++i)
#pragma unroll
        for (int j = 0; j < 4; ++j)
            acc[i][j] = f32x4{0.f, 0.f, 0.f, 0.f};
}

// ---------------------------------------------------------------------------
// single cast dispatch: x -> x16, Wq|Wk|Wv -> w16, and zero rowsum.
// ---------------------------------------------------------------------------
__global__ __launch_bounds__(256) void cvt_all(
    const float4* __restrict__ x,  const float4* __restrict__ wq,
    const float4* __restrict__ wk, const float4* __restrict__ wv,
    ushort4* __restrict__ x16, ushort4* __restrict__ w16,
    float4* __restrict__ rsum4)
{
    constexpr int NX = CBS * CD / 4;        // 1572864
    constexpr int NW = CD * CD / 4;         // 147456
    constexpr int NT = NX + 3 * NW;         // 2015232 (divisible by 256)
    const int i = blockIdx.x * 256 + threadIdx.x;
    if (i < NX) {
        x16[i] = cvt4(x[i]);
    } else if (i < NT) {
        const int j = i - NX;
        if (j < NW)            w16[j] = cvt4(wq[j]);
        else if (j < 2 * NW)   w16[j] = cvt4(wk[j - NW]);
        else                   w16[j] = cvt4(wv[j - 2 * NW]);
    } else {
        const int j = i - NT;               // 0..2047 : zero rowsum (8192 f32)
        rsum4[j] = float4{0.f, 0.f, 0.f, 0.f};
    }
}

// ---------------------------------------------------------------------------
// 2-phase GEMM core (qk): acc[MI][4] += A[m,k]*B[n,k], BM x 128 tile, BK=32
// double-buffered prefetch.
// ---------------------------------------------------------------------------
template <int BM>
__device__ __forceinline__ void gemm_core(
    const __hip_bfloat16* __restrict__ A,
    const __hip_bfloat16* __restrict__ B,
    __hip_bfloat16* As, __hip_bfloat16* Bs,
    int m0, int n0, int K, int kend,
    f32x4 (&acc)[BM / 32][4])
{
    constexpr int AC = BM / 16;
    constexpr int SC = AC + 8;
    constexpr int MI = BM / 32;

    const int t  = threadIdx.x;
    const int w  = t >> 6;
    const int l  = t & 63;
    const int lq = l >> 4;
    const int lm = l & 15;
    const int wm = (w >> 1) * (BM / 2);
    const int wn = (w & 1) * 64;

    const int srow = l >> 2;
    const int scol = (l & 3) * 8;

    auto stage = [&](int buf, int k0) {
#pragma unroll
        for (int ci = 0; ci < SC / 4; ++ci) {
            const int c = ci * 4 + w;
            if (c < AC) {
                __builtin_amdgcn_global_load_lds(
                    GPTR(A + (size_t)(m0 + c * 16 + srow) * K + k0 + scol),
                    LPTR(&As[buf * BM * 32 + c * 512]), 16, 0, 0);
            } else {
                const int c2 = c - AC;
                __builtin_amdgcn_global_load_lds(
                    GPTR(B + (size_t)(n0 + c2 * 16 + srow) * K + k0 + scol),
                    LPTR(&Bs[buf * 128 * 32 + c2 * 512]), 16, 0, 0);
            }
        }
    };

    stage(0, 0);
    asm volatile("s_waitcnt vmcnt(0)" ::: "memory");
    __syncthreads();

    int cur = 0;
    for (int k0 = 0; k0 < kend; k0 += 32) {
        if (k0 + 32 < kend)
            stage(cur ^ 1, k0 + 32);

        short8 af[MI], bf[4];
#pragma unroll
        for (int i = 0; i < MI; ++i)
            af[i] = *(const short8*)&As[cur * BM * 32 + (wm + i * 16 + lm) * 32 + lq * 8];
#pragma unroll
        for (int j = 0; j < 4; ++j)
            bf[j] = *(const short8*)&Bs[cur * 128 * 32 + (wn + j * 16 + lm) * 32 + lq * 8];

#pragma unroll
        for (int i = 0; i < MI; ++i)
#pragma unroll
            for (int j = 0; j < 4; ++j)
                acc[i][j] = __builtin_amdgcn_mfma_f32_16x16x32_bf16(
                    af[i], bf[j], acc[i][j], 0, 0, 0);

        __syncthreads();
        cur ^= 1;
    }
}

// ---------------------------------------------------------------------------
// Q/K projections, 128x128 tiles, 768 blocks (Q: 0..383, K: 384..767).
// Uniform durations -> XCD swizzle safe.
// ---------------------------------------------------------------------------
__global__ __launch_bounds__(256) void qk_gemm(
    const __hip_bfloat16* __restrict__ x16,
    const __hip_bfloat16* __restrict__ w16,
    __hip_bfloat16* __restrict__ q16,
    __hip_bfloat16* __restrict__ k16)
{
    __shared__ __align__(16) __hip_bfloat16 As[2 * 128 * 32];   // 16 KB
    __shared__ __align__(16) __hip_bfloat16 Bs[2 * 128 * 32];   // 16 KB

    const int id   = xcd_swz(blockIdx.x, 768);   // 0..767
    const int proj = id / 384;            // 0=Q, 1=K
    const int r    = id % 384;
    const int n0   = (r % 6) * 128;
    const int m0   = (r / 6) * 128;

    f32x4 acc[4][4];
    zero_acc<4>(acc);
    gemm_core<128>(x16, w16 + (size_t)proj * CD * CD, As, Bs, m0, n0, CD, CD, acc);

    __hip_bfloat16* C = proj ? k16 : q16;
    const int t  = threadIdx.x;
    const int w  = t >> 6;
    const int l  = t & 63;
    const int lq = l >> 4;
    const int lm = l & 15;
    const int wm = (w >> 1) * 64;
    const int wn = (w & 1) * 64;
#pragma unroll
    for (int i = 0; i < 4; ++i)
#pragma unroll
        for (int j = 0; j < 4; ++j) {
            const int n = n0 + wn + j * 16 + lm;
#pragma unroll
            for (int r2 = 0; r2 < 4; ++r2) {
                const int m = m0 + wm + i * 16 + lq * 4 + r2;
                C[(size_t)m * CD + n] = __float2bfloat16(acc[i][j][r2]);
            }
        }
}

// ---------------------------------------------------------------------------
// gemm64 core: 64x128 tile, BK=64 (two 32-slabs staged together), double-
// buffered prefetch. Per iteration: 12 load-ops || 16 MFMA, ONE barrier+drain
// per 64 K-elements. LDS: As[2][2][64][32] = 16 KB, Bs[2][2][128][32] = 32 KB.
// kend must be a multiple of 64. Measured ~570 TF at 3 blocks/CU (pv, R8).
// ---------------------------------------------------------------------------
__device__ __forceinline__ void gemm64_core(
    const __hip_bfloat16* __restrict__ A,
    const __hip_bfloat16* __restrict__ B,
    __hip_bfloat16* As, __hip_bfloat16* Bs,
    int m0, int n0, int K, int kend,
    f32x4 (&acc)[2][4])
{
    constexpr int AC = 4;           // A chunks (16 rows x 32 cols) per slab
    constexpr int SC = AC + 8;      // 12 chunks per slab

    const int t  = threadIdx.x;
    const int w  = t >> 6;
    const int l  = t & 63;
    const int lq = l >> 4;
    const int lm = l & 15;
    const int wm = (w >> 1) * 32;
    const int wn = (w & 1) * 64;

    const int srow = l >> 2;
    const int scol = (l & 3) * 8;

    auto stage = [&](int buf, int k0) {
#pragma unroll
        for (int ci = 0; ci < 2 * SC / 4; ++ci) {
            const int c    = ci * 4 + w;
            const int slab = (c >= SC) ? 1 : 0;
            const int cc   = c - slab * SC;
            const int kofs = k0 + slab * 32 + scol;
            if (cc < AC) {
                __builtin_amdgcn_global_load_lds(
                    GPTR(A + (size_t)(m0 + cc * 16 + srow) * K + kofs),
                    LPTR(&As[buf * 4096 + slab * 2048 + cc * 512]), 16, 0, 0);
            } else {
                const int c2 = cc - AC;
                __builtin_amdgcn_global_load_lds(
                    GPTR(B + (size_t)(n0 + c2 * 16 + srow) * K + kofs),
                    LPTR(&Bs[buf * 8192 + slab * 4096 + c2 * 512]), 16, 0, 0);
            }
        }
    };

    stage(0, 0);
    asm volatile("s_waitcnt vmcnt(0)" ::: "memory");
    __syncthreads();

    int cur = 0;
    for (int k0 = 0; k0 < kend; k0 += 64) {
        if (k0 + 64 < kend)
            stage(cur ^ 1, k0 + 64);        // prefetch overlaps the MFMAs below

#pragma unroll
        for (int kk = 0; kk < 2; ++kk) {
            short8 af[2], bf[4];
#pragma unroll
            for (int i = 0; i < 2; ++i)
                af[i] = *(const short8*)&As[cur * 4096 + kk * 2048 + (wm + i * 16 + lm) * 32 + lq * 8];
#pragma unroll
            for (int j = 0; j < 4; ++j)
                bf[j] = *(const short8*)&Bs[cur * 8192 + kk * 4096 + (wn + j * 16 + lm) * 32 + lq * 8];
#pragma unroll
            for (int i = 0; i < 2; ++i)
#pragma unroll
                for (int j = 0; j < 4; ++j)
                    acc[i][j] = __builtin_amdgcn_mfma_f32_16x16x32_bf16(
                        af[i], bf[j], acc[i][j], 0, 0, 0);
        }

        __syncthreads();
        cur ^= 1;
    }
}

// ---------------------------------------------------------------------------
// scores (1088 compact-causal 64x128 tiles: E=exp(scale*QK^T), rowsum
// atomics) + V^T projection (768 64x128 tiles) in one 1856-block dispatch.
// All blocks K=768 -> uniform duration -> XCD swizzle safe.
// Compact causal decode (R5-baseline, verified): tiles per m-row mi =
// floor(mi/2)+1; cumulative C(2a)=a(a+1), C(2a+1)=(a+1)^2.
// ---------------------------------------------------------------------------
__global__ __launch_bounds__(256) void scores_vt_gemm(
    const __hip_bfloat16* __restrict__ q16,
    const __hip_bfloat16* __restrict__ k16,
    const __hip_bfloat16* __restrict__ x16,
    const __hip_bfloat16* __restrict__ w16,
    __hip_bfloat16* __restrict__ sp16,
    __hip_bfloat16* __restrict__ vt16,
    float* __restrict__ rowsum,
    float scale)
{
    __shared__ __align__(16) __hip_bfloat16 As[2 * 4096];   // 16 KB
    __shared__ __align__(16) __hip_bfloat16 Bs[2 * 8192];   // 32 KB

    const int id = xcd_swz(blockIdx.x, 1856);    // 0..1855
    const bool is_sc = (id < 1088);
    const __hip_bfloat16 *A, *B;
    int m0, n0, b;

    if (is_sc) {
        b = id & 3;
        const int tt = id >> 2;           // 0..271
        int s = (int)sqrtf((float)tt);
        while ((s + 1) * (s + 1) <= tt) ++s;
        while (s * s > tt) --s;
        int mi, nj;
        if (tt < s * (s + 1)) { mi = 2 * s - 1; nj = tt - s * s; }
        else                  { mi = 2 * s;     nj = tt - s * (s + 1); }
        m0 = mi * 64;
        n0 = nj * 128;
        A = q16 + (size_t)b * CS * CD;
        B = k16 + (size_t)b * CS * CD;
    } else {
        int r = id - 1088;                // 0..767
        b = r / 192; r %= 192;
        m0 = (r / 16) * 64;               // d-tile (12 of 64)
        n0 = (r % 16) * 128;              // s-tile (16 of 128)
        A = w16 + (size_t)2 * CD * CD;    // Wv
        B = x16 + (size_t)b * CS * CD;
    }

    f32x4 acc[2][4];
    zero_acc<2>(acc);
    gemm64_core(A, B, As, Bs, m0, n0, CD, CD, acc);

    const int t  = threadIdx.x;
    const int w  = t >> 6;
    const int l  = t & 63;
    const int lq = l >> 4;
    const int lm = l & 15;
    const int wm = (w >> 1) * 32;
    const int wn = (w & 1) * 64;

    if (is_sc) {
        __hip_bfloat16* C = sp16 + (size_t)b * CS * CS;
        float* rs = rowsum + (size_t)b * CS;
#pragma unroll
        for (int i = 0; i < 2; ++i) {
            float psum[4] = {0.f, 0.f, 0.f, 0.f};
#pragma unroll
            for (int j = 0; j < 4; ++j) {
                const int n = n0 + wn + j * 16 + lm;
#pragma unroll
                for (int r2 = 0; r2 < 4; ++r2) {
                    const int m = m0 + wm + i * 16 + lq * 4 + r2;
                    float e = (n <= m) ? __expf(acc[i][j][r2] * scale) : 0.f;
                    C[(size_t)m * CS + n] = __float2bfloat16(e);
                    psum[r2] += e;
                }
            }
#pragma unroll
            for (int r2 = 0; r2 < 4; ++r2) {
#pragma unroll
                for (int off = 1; off < 16; off <<= 1)
                    psum[r2] += __shfl_xor(psum[r2], off);
                if (lm == 0) {
                    const int m = m0 + wm + i * 16 + lq * 4 + r2;
                    atomicAdd(&rs[m], psum[r2]);
                }
            }
        }
    } else {
        __hip_bfloat16* C = vt16 + (size_t)b * CD * CS;
#pragma unroll
        for (int i = 0; i < 2; ++i)
#pragma unroll
            for (int j = 0; j < 4; ++j) {
                const int n = n0 + wn + j * 16 + lm;
#pragma unroll
                for (int r2 = 0; r2 < 4; ++r2) {
                    const int m = m0 + wm + i * 16 + lq * 4 + r2;
                    C[(size_t)m * CS + n] = __float2bfloat16(acc[i][j][r2]);
                }
            }
    }
}

// ---------------------------------------------------------------------------
// out[b] = (E[b] @ Vt[b]^T) / rowsum, 64x128 tiles, kend = m0+64,
// heavy-first (LPT) ordering, no XCD swizzle (R7 lesson). (R8-verified ~23 us)
// ---------------------------------------------------------------------------
__global__ __launch_bounds__(256) void pv_gemm(
    const __hip_bfloat16* __restrict__ sp16,
    const __hip_bfloat16* __restrict__ vt16,
    const float* __restrict__ rowsum,
    float* __restrict__ out)
{
    const int id   = blockIdx.x;        // 0..767
    const int mrev = id / 24;
    int r          = id % 24;
    const int b    = r / 6;
    const int n0   = (r % 6) * 128;
    const int mi   = 31 - mrev;         // heavy (large kend) first
    const int m0   = mi * 64;
    const int kend = m0 + 64;

    __shared__ __align__(16) __hip_bfloat16 As[2 * 4096];   // 16 KB
    __shared__ __align__(16) __hip_bfloat16 Bs[2 * 8192];   // 32 KB

    const __hip_bfloat16* A = sp16 + (size_t)b * CS * CS;
    const __hip_bfloat16* B = vt16 + (size_t)b * CD * CS;
    float* Co = out + (size_t)b * CS * CD;
    const float* rs = rowsum + (size_t)b * CS;

    f32x4 acc[2][4];
    zero_acc<2>(acc);
    gemm64_core(A, B, As, Bs, m0, n0, CS, kend, acc);

    const int t  = threadIdx.x;
    const int w  = t >> 6;
    const int l  = t & 63;
    const int lq = l >> 4;
    const int lm = l & 15;
    const int wm = (w >> 1) * 32;
    const int wn = (w & 1) * 64;

#pragma unroll
    for (int i = 0; i < 2; ++i) {
        float inv[4];
#pragma unroll
        for (int r2 = 0; r2 < 4; ++r2)
            inv[r2] = 1.0f / rs[m0 + wm + i * 16 + lq * 4 + r2];
#pragma unroll
        for (int j = 0; j < 4; ++j) {
            const int n = n0 + wn + j * 16 + lm;
#pragma unroll
            for (int r2 = 0; r2 < 4; ++r2) {
                const int m = m0 + wm + i * 16 + lq * 4 + r2;
                Co[(size_t)m * CD + n] = acc[i][j][r2] * inv[r2];
            }
        }
    }
}

// ---------------------------------------------------------------------------
// Launch
// ---------------------------------------------------------------------------
extern "C" void kernel_launch(void* const* d_in, const int* in_sizes, int n_in,
                              void* d_out, int out_size, void* d_ws, size_t ws_size,
                              hipStream_t stream)
{
    const float* x  = (const float*)d_in[0];
    const float* Wq = (const float*)d_in[1];
    const float* Wk = (const float*)d_in[2];
    const float* Wv = (const float*)d_in[3];
    float* out = (float*)d_out;

    char* ws = (char*)d_ws;
    size_t off = 0;
    auto alloc = [&](size_t bytes) { char* p = ws + off; off += bytes; return p; };

    __hip_bfloat16* x16  = (__hip_bfloat16*)alloc((size_t)CBS * CD * 2);
    __hip_bfloat16* q16  = (__hip_bfloat16*)alloc((size_t)CBS * CD * 2);
    __hip_bfloat16* k16  = (__hip_bfloat16*)alloc((size_t)CBS * CD * 2);
    __hip_bfloat16* vt16 = (__hip_bfloat16*)alloc((size_t)CBS * CD * 2);   // [B][D][S]
    __hip_bfloat16* sp16 = (__hip_bfloat16*)alloc((size_t)CB * CS * CS * 2);
    __hip_bfloat16* w16  = (__hip_bfloat16*)alloc((size_t)3 * CD * CD * 2);
    float*          rsum = (float*)alloc((size_t)CB * CS * sizeof(float));

    constexpr int NCVT_BLK = (CBS * CD + 3 * CD * CD) / 4 / 256 + 8;
    cvt_all<<<NCVT_BLK, 256, 0, stream>>>(
        (const float4*)x, (const float4*)Wq, (const float4*)Wk, (const float4*)Wv,
        (ushort4*)x16, (ushort4*)w16, (float4*)rsum);

    qk_gemm<<<768, 256, 0, stream>>>(x16, w16, q16, k16);

    scores_vt_gemm<<<1856, 256, 0, stream>>>(
        q16, k16, x16, w16, sp16, vt16, rsum, 0.03608439182435161f);

    pv_gemm<<<768, 256, 0, stream>>>(sp16, vt16, rsum, out);
}

// Round 10
// 184.385 us; speedup vs baseline: 1.0580x; 1.0580x over previous
//
#include <hip/hip_runtime.h>
#include <hip/hip_bf16.h>
#include <cstdint>
#include <cstddef>

// B=4, S=2048, D=768 single-head causal attention, fp32 I/O.
// Round 15: gemm64 core (sv + pv) gets the verified 8-phase LDS layout to
// kill its 8-way ds_read_b128 bank conflict (R9: 4.28M conflict-cycles on sv,
// 2.4M on pv). Old layout: 64B rows -> read addr = lm*64 + lq*16 -> bank bits
// {lm&1, lq} -> 8 bank-groups for 64 lanes. New layout: 128B rows (64 bf16)
// + granule XOR swizzle -- LDS(row, g) holds global granule g^(row&7);
// staging keeps the linear wave-uniform dest (global_load_lds requirement)
// and pre-swizzles the PER-LANE GLOBAL source (rule 21 / m173); reads use
// c0=(lq^(lm&7))*8, c1=c0^32 (verbatim the 8-phase algebra, 0 conflicts
// measured R2-R8). Call counts (6/wave/K-tile), LDS totals (48 KB), and the
// one-drain-per-64K prefetch structure are unchanged -- address math only.
// qk (BK=32 core) untouched this round. Session-noise note: totals carry
// +-10-20 us across container sessions; per-kernel rocprof is the signal.

typedef __attribute__((ext_vector_type(8))) short short8;   // 8 x bf16
typedef __attribute__((ext_vector_type(4))) float f32x4;    // MFMA C/D

#define GPTR(p) (const __attribute__((address_space(1))) void*)(p)
#define LPTR(p) (__attribute__((address_space(3))) void*)(p)

constexpr int CB = 4, CS = 2048, CD = 768;
constexpr int CBS = CB * CS;            // 8192

// T1: XCD-aware bijective swizzle (requires nwg % 8 == 0). Only for grids
// with uniform block durations (R7 lesson: never on LPT grids).
__device__ __forceinline__ int xcd_swz(int bid, int nwg) {
    return (bid & 7) * (nwg >> 3) + (bid >> 3);
}

__device__ inline unsigned short f2bf_bits(float v) {
    __hip_bfloat16 h = __float2bfloat16(v);
    unsigned short u;
    __builtin_memcpy(&u, &h, 2);
    return u;
}

__device__ inline ushort4 cvt4(float4 f) {
    ushort4 u;
    u.x = f2bf_bits(f.x); u.y = f2bf_bits(f.y);
    u.z = f2bf_bits(f.z); u.w = f2bf_bits(f.w);
    return u;
}

template <int MI>
__device__ __forceinline__ void zero_acc(f32x4 (&acc)[MI][4]) {
#pragma unroll
    for (int i = 0; i < MI; ++i)
#pragma unroll
        for (int j = 0; j < 4; ++j)
            acc[i][j] = f32x4{0.f, 0.f, 0.f, 0.f};
}

// ---------------------------------------------------------------------------
// single cast dispatch: x -> x16, Wq|Wk|Wv -> w16, and zero rowsum.
// ---------------------------------------------------------------------------
__global__ __launch_bounds__(256) void cvt_all(
    const float4* __restrict__ x,  const float4* __restrict__ wq,
    const float4* __restrict__ wk, const float4* __restrict__ wv,
    ushort4* __restrict__ x16, ushort4* __restrict__ w16,
    float4* __restrict__ rsum4)
{
    constexpr int NX = CBS * CD / 4;        // 1572864
    constexpr int NW = CD * CD / 4;         // 147456
    constexpr int NT = NX + 3 * NW;         // 2015232 (divisible by 256)
    const int i = blockIdx.x * 256 + threadIdx.x;
    if (i < NX) {
        x16[i] = cvt4(x[i]);
    } else if (i < NT) {
        const int j = i - NX;
        if (j < NW)            w16[j] = cvt4(wq[j]);
        else if (j < 2 * NW)   w16[j] = cvt4(wk[j - NW]);
        else                   w16[j] = cvt4(wv[j - 2 * NW]);
    } else {
        const int j = i - NT;               // 0..2047 : zero rowsum (8192 f32)
        rsum4[j] = float4{0.f, 0.f, 0.f, 0.f};
    }
}

// ---------------------------------------------------------------------------
// 2-phase GEMM core (qk): acc[MI][4] += A[m,k]*B[n,k], BM x 128 tile, BK=32
// double-buffered prefetch.  (unchanged this round)
// ---------------------------------------------------------------------------
template <int BM>
__device__ __forceinline__ void gemm_core(
    const __hip_bfloat16* __restrict__ A,
    const __hip_bfloat16* __restrict__ B,
    __hip_bfloat16* As, __hip_bfloat16* Bs,
    int m0, int n0, int K, int kend,
    f32x4 (&acc)[BM / 32][4])
{
    constexpr int AC = BM / 16;
    constexpr int SC = AC + 8;
    constexpr int MI = BM / 32;

    const int t  = threadIdx.x;
    const int w  = t >> 6;
    const int l  = t & 63;
    const int lq = l >> 4;
    const int lm = l & 15;
    const int wm = (w >> 1) * (BM / 2);
    const int wn = (w & 1) * 64;

    const int srow = l >> 2;
    const int scol = (l & 3) * 8;

    auto stage = [&](int buf, int k0) {
#pragma unroll
        for (int ci = 0; ci < SC / 4; ++ci) {
            const int c = ci * 4 + w;
            if (c < AC) {
                __builtin_amdgcn_global_load_lds(
                    GPTR(A + (size_t)(m0 + c * 16 + srow) * K + k0 + scol),
                    LPTR(&As[buf * BM * 32 + c * 512]), 16, 0, 0);
            } else {
                const int c2 = c - AC;
                __builtin_amdgcn_global_load_lds(
                    GPTR(B + (size_t)(n0 + c2 * 16 + srow) * K + k0 + scol),
                    LPTR(&Bs[buf * 128 * 32 + c2 * 512]), 16, 0, 0);
            }
        }
    };

    stage(0, 0);
    asm volatile("s_waitcnt vmcnt(0)" ::: "memory");
    __syncthreads();

    int cur = 0;
    for (int k0 = 0; k0 < kend; k0 += 32) {
        if (k0 + 32 < kend)
            stage(cur ^ 1, k0 + 32);

        short8 af[MI], bf[4];
#pragma unroll
        for (int i = 0; i < MI; ++i)
            af[i] = *(const short8*)&As[cur * BM * 32 + (wm + i * 16 + lm) * 32 + lq * 8];
#pragma unroll
        for (int j = 0; j < 4; ++j)
            bf[j] = *(const short8*)&Bs[cur * 128 * 32 + (wn + j * 16 + lm) * 32 + lq * 8];

#pragma unroll
        for (int i = 0; i < MI; ++i)
#pragma unroll
            for (int j = 0; j < 4; ++j)
                acc[i][j] = __builtin_amdgcn_mfma_f32_16x16x32_bf16(
                    af[i], bf[j], acc[i][j], 0, 0, 0);

        __syncthreads();
        cur ^= 1;
    }
}

// ---------------------------------------------------------------------------
// Q/K projections, 128x128 tiles, 768 blocks (Q: 0..383, K: 384..767).
// Uniform durations -> XCD swizzle safe.
// ---------------------------------------------------------------------------
__global__ __launch_bounds__(256) void qk_gemm(
    const __hip_bfloat16* __restrict__ x16,
    const __hip_bfloat16* __restrict__ w16,
    __hip_bfloat16* __restrict__ q16,
    __hip_bfloat16* __restrict__ k16)
{
    __shared__ __align__(16) __hip_bfloat16 As[2 * 128 * 32];   // 16 KB
    __shared__ __align__(16) __hip_bfloat16 Bs[2 * 128 * 32];   // 16 KB

    const int id   = xcd_swz(blockIdx.x, 768);   // 0..767
    const int proj = id / 384;            // 0=Q, 1=K
    const int r    = id % 384;
    const int n0   = (r % 6) * 128;
    const int m0   = (r / 6) * 128;

    f32x4 acc[4][4];
    zero_acc<4>(acc);
    gemm_core<128>(x16, w16 + (size_t)proj * CD * CD, As, Bs, m0, n0, CD, CD, acc);

    __hip_bfloat16* C = proj ? k16 : q16;
    const int t  = threadIdx.x;
    const int w  = t >> 6;
    const int l  = t & 63;
    const int lq = l >> 4;
    const int lm = l & 15;
    const int wm = (w >> 1) * 64;
    const int wn = (w & 1) * 64;
#pragma unroll
    for (int i = 0; i < 4; ++i)
#pragma unroll
        for (int j = 0; j < 4; ++j) {
            const int n = n0 + wn + j * 16 + lm;
#pragma unroll
            for (int r2 = 0; r2 < 4; ++r2) {
                const int m = m0 + wm + i * 16 + lq * 4 + r2;
                C[(size_t)m * CD + n] = __float2bfloat16(acc[i][j][r2]);
            }
        }
}

// ---------------------------------------------------------------------------
// gemm64 core (SWIZZLED): 64x128 tile, BK=64, double-buffered prefetch, one
// barrier+drain per 64 K-elements.
// LDS layout: As[buf][row 0..63][gran 0..7]  (row stride 64 bf16 = 128 B),
//             Bs[buf][row 0..127][gran 0..7] -- LDS(row,g) holds global
// 16B-granule g^(row&7) of that row's 64-k slice (involution; same algebra as
// the verified 8-phase core). Staging: 24 wave-calls (A:8, B:16), dest =
// wave-uniform base + lane*16B (linear), source per-lane pre-swizzled.
// Reads: c0=(lq^(lm&7))*8, c1=c0^32 -> conflict-free (0 measured, R2-R8).
// LDS: As 2x8KB, Bs 2x16KB = 48 KB total (unchanged). kend: multiple of 64.
// ---------------------------------------------------------------------------
__device__ __forceinline__ void gemm64_core(
    const __hip_bfloat16* __restrict__ A,
    const __hip_bfloat16* __restrict__ B,
    __hip_bfloat16* As, __hip_bfloat16* Bs,
    int m0, int n0, int K, int kend,
    f32x4 (&acc)[2][4])
{
    const int t  = threadIdx.x;
    const int w  = t >> 6;
    const int l  = t & 63;
    const int lq = l >> 4;
    const int lm = l & 15;
    const int wm = (w >> 1) * 32;
    const int wn = (w & 1) * 64;

    const int lrow8 = l >> 3;         // row within an 8-row staging call
    const int gl    = l & 7;          // LDS granule this lane fills
    const int c0    = (lq ^ (lm & 7)) * 8;   // swizzled read granule, slab 0
    const int c1    = c0 ^ 32;               // slab 1 (granule bit2 = +32 bf16)

    auto stage = [&](int buf, int k0) {
#pragma unroll
        for (int ci = 0; ci < 6; ++ci) {
            const int c = ci * 4 + w;         // wave-uniform call id, 0..23
            if (c < 8) {                      // A: 8 calls x 8 rows
                const int r0  = c * 8;
                const int row = r0 + lrow8;
                const int gg  = gl ^ (row & 7);
                __builtin_amdgcn_global_load_lds(
                    GPTR(A + (size_t)(m0 + row) * K + k0 + gg * 8),
                    LPTR(&As[buf * 4096 + r0 * 64]), 16, 0, 0);
            } else {                          // B: 16 calls x 8 rows
                const int cb  = c - 8;
                const int r0  = cb * 8;
                const int row = r0 + lrow8;
                const int gg  = gl ^ (row & 7);
                __builtin_amdgcn_global_load_lds(
                    GPTR(B + (size_t)(n0 + row) * K + k0 + gg * 8),
                    LPTR(&Bs[buf * 8192 + r0 * 64]), 16, 0, 0);
            }
        }
    };

    stage(0, 0);
    asm volatile("s_waitcnt vmcnt(0)" ::: "memory");
    __syncthreads();

    int cur = 0;
    for (int k0 = 0; k0 < kend; k0 += 64) {
        if (k0 + 64 < kend)
            stage(cur ^ 1, k0 + 64);        // prefetch overlaps the MFMAs below

#pragma unroll
        for (int kk = 0; kk < 2; ++kk) {
            const int cg = kk ? c1 : c0;
            short8 af[2], bf[4];
#pragma unroll
            for (int i = 0; i < 2; ++i)
                af[i] = *(const short8*)&As[cur * 4096 + (wm + i * 16 + lm) * 64 + cg];
#pragma unroll
            for (int j = 0; j < 4; ++j)
                bf[j] = *(const short8*)&Bs[cur * 8192 + (wn + j * 16 + lm) * 64 + cg];
#pragma unroll
            for (int i = 0; i < 2; ++i)
#pragma unroll
                for (int j = 0; j < 4; ++j)
                    acc[i][j] = __builtin_amdgcn_mfma_f32_16x16x32_bf16(
                        af[i], bf[j], acc[i][j], 0, 0, 0);
        }

        __syncthreads();
        cur ^= 1;
    }
}

// ---------------------------------------------------------------------------
// scores (1088 compact-causal 64x128 tiles: E=exp(scale*QK^T), rowsum
// atomics) + V^T projection (768 64x128 tiles) in one 1856-block dispatch.
// All blocks K=768 -> uniform duration -> XCD swizzle safe.
// ---------------------------------------------------------------------------
__global__ __launch_bounds__(256) void scores_vt_gemm(
    const __hip_bfloat16* __restrict__ q16,
    const __hip_bfloat16* __restrict__ k16,
    const __hip_bfloat16* __restrict__ x16,
    const __hip_bfloat16* __restrict__ w16,
    __hip_bfloat16* __restrict__ sp16,
    __hip_bfloat16* __restrict__ vt16,
    float* __restrict__ rowsum,
    float scale)
{
    __shared__ __align__(16) __hip_bfloat16 As[2 * 4096];   // 16 KB
    __shared__ __align__(16) __hip_bfloat16 Bs[2 * 8192];   // 32 KB

    const int id = xcd_swz(blockIdx.x, 1856);    // 0..1855
    const bool is_sc = (id < 1088);
    const __hip_bfloat16 *A, *B;
    int m0, n0, b;

    if (is_sc) {
        b = id & 3;
        const int tt = id >> 2;           // 0..271
        int s = (int)sqrtf((float)tt);
        while ((s + 1) * (s + 1) <= tt) ++s;
        while (s * s > tt) --s;
        int mi, nj;
        if (tt < s * (s + 1)) { mi = 2 * s - 1; nj = tt - s * s; }
        else                  { mi = 2 * s;     nj = tt - s * (s + 1); }
        m0 = mi * 64;
        n0 = nj * 128;
        A = q16 + (size_t)b * CS * CD;
        B = k16 + (size_t)b * CS * CD;
    } else {
        int r = id - 1088;                // 0..767
        b = r / 192; r %= 192;
        m0 = (r / 16) * 64;               // d-tile (12 of 64)
        n0 = (r % 16) * 128;              // s-tile (16 of 128)
        A = w16 + (size_t)2 * CD * CD;    // Wv
        B = x16 + (size_t)b * CS * CD;
    }

    f32x4 acc[2][4];
    zero_acc<2>(acc);
    gemm64_core(A, B, As, Bs, m0, n0, CD, CD, acc);

    const int t  = threadIdx.x;
    const int w  = t >> 6;
    const int l  = t & 63;
    const int lq = l >> 4;
    const int lm = l & 15;
    const int wm = (w >> 1) * 32;
    const int wn = (w & 1) * 64;

    if (is_sc) {
        __hip_bfloat16* C = sp16 + (size_t)b * CS * CS;
        float* rs = rowsum + (size_t)b * CS;
#pragma unroll
        for (int i = 0; i < 2; ++i) {
            float psum[4] = {0.f, 0.f, 0.f, 0.f};
#pragma unroll
            for (int j = 0; j < 4; ++j) {
                const int n = n0 + wn + j * 16 + lm;
#pragma unroll
                for (int r2 = 0; r2 < 4; ++r2) {
                    const int m = m0 + wm + i * 16 + lq * 4 + r2;
                    float e = (n <= m) ? __expf(acc[i][j][r2] * scale) : 0.f;
                    C[(size_t)m * CS + n] = __float2bfloat16(e);
                    psum[r2] += e;
                }
            }
#pragma unroll
            for (int r2 = 0; r2 < 4; ++r2) {
#pragma unroll
                for (int off = 1; off < 16; off <<= 1)
                    psum[r2] += __shfl_xor(psum[r2], off);
                if (lm == 0) {
                    const int m = m0 + wm + i * 16 + lq * 4 + r2;
                    atomicAdd(&rs[m], psum[r2]);
                }
            }
        }
    } else {
        __hip_bfloat16* C = vt16 + (size_t)b * CD * CS;
#pragma unroll
        for (int i = 0; i < 2; ++i)
#pragma unroll
            for (int j = 0; j < 4; ++j) {
                const int n = n0 + wn + j * 16 + lm;
#pragma unroll
                for (int r2 = 0; r2 < 4; ++r2) {
                    const int m = m0 + wm + i * 16 + lq * 4 + r2;
                    C[(size_t)m * CS + n] = __float2bfloat16(acc[i][j][r2]);
                }
            }
    }
}

// ---------------------------------------------------------------------------
// out[b] = (E[b] @ Vt[b]^T) / rowsum, 64x128 tiles, kend = m0+64,
// heavy-first (LPT) ordering, no XCD swizzle (R7 lesson).
// ---------------------------------------------------------------------------
__global__ __launch_bounds__(256) void pv_gemm(
    const __hip_bfloat16* __restrict__ sp16,
    const __hip_bfloat16* __restrict__ vt16,
    const float* __restrict__ rowsum,
    float* __restrict__ out)
{
    const int id   = blockIdx.x;        // 0..767
    const int mrev = id / 24;
    int r          = id % 24;
    const int b    = r / 6;
    const int n0   = (r % 6) * 128;
    const int mi   = 31 - mrev;         // heavy (large kend) first
    const int m0   = mi * 64;
    const int kend = m0 + 64;

    __shared__ __align__(16) __hip_bfloat16 As[2 * 4096];   // 16 KB
    __shared__ __align__(16) __hip_bfloat16 Bs[2 * 8192];   // 32 KB

    const __hip_bfloat16* A = sp16 + (size_t)b * CS * CS;
    const __hip_bfloat16* B = vt16 + (size_t)b * CD * CS;
    float* Co = out + (size_t)b * CS * CD;
    const float* rs = rowsum + (size_t)b * CS;

    f32x4 acc[2][4];
    zero_acc<2>(acc);
    gemm64_core(A, B, As, Bs, m0, n0, CS, kend, acc);

    const int t  = threadIdx.x;
    const int w  = t >> 6;
    const int l  = t & 63;
    const int lq = l >> 4;
    const int lm = l & 15;
    const int wm = (w >> 1) * 32;
    const int wn = (w & 1) * 64;

#pragma unroll
    for (int i = 0; i < 2; ++i) {
        float inv[4];
#pragma unroll
        for (int r2 = 0; r2 < 4; ++r2)
            inv[r2] = 1.0f / rs[m0 + wm + i * 16 + lq * 4 + r2];
#pragma unroll
        for (int j = 0; j < 4; ++j) {
            const int n = n0 + wn + j * 16 + lm;
#pragma unroll
            for (int r2 = 0; r2 < 4; ++r2) {
                const int m = m0 + wm + i * 16 + lq * 4 + r2;
                Co[(size_t)m * CD + n] = acc[i][j][r2] * inv[r2];
            }
        }
    }
}

// ---------------------------------------------------------------------------
// Launch
// ---------------------------------------------------------------------------
extern "C" void kernel_launch(void* const* d_in, const int* in_sizes, int n_in,
                              void* d_out, int out_size, void* d_ws, size_t ws_size,
                              hipStream_t stream)
{
    const float* x  = (const float*)d_in[0];
    const float* Wq = (const float*)d_in[1];
    const float* Wk = (const float*)d_in[2];
    const float* Wv = (const float*)d_in[3];
    float* out = (float*)d_out;

    char* ws = (char*)d_ws;
    size_t off = 0;
    auto alloc = [&](size_t bytes) { char* p = ws + off; off += bytes; return p; };

    __hip_bfloat16* x16  = (__hip_bfloat16*)alloc((size_t)CBS * CD * 2);
    __hip_bfloat16* q16  = (__hip_bfloat16*)alloc((size_t)CBS * CD * 2);
    __hip_bfloat16* k16  = (__hip_bfloat16*)alloc((size_t)CBS * CD * 2);
    __hip_bfloat16* vt16 = (__hip_bfloat16*)alloc((size_t)CBS * CD * 2);   // [B][D][S]
    __hip_bfloat16* sp16 = (__hip_bfloat16*)alloc((size_t)CB * CS * CS * 2);
    __hip_bfloat16* w16  = (__hip_bfloat16*)alloc((size_t)3 * CD * CD * 2);
    float*          rsum = (float*)alloc((size_t)CB * CS * sizeof(float));

    constexpr int NCVT_BLK = (CBS * CD + 3 * CD * CD) / 4 / 256 + 8;
    cvt_all<<<NCVT_BLK, 256, 0, stream>>>(
        (const float4*)x, (const float4*)Wq, (const float4*)Wk, (const float4*)Wv,
        (ushort4*)x16, (ushort4*)w16, (float4*)rsum);

    qk_gemm<<<768, 256, 0, stream>>>(x16, w16, q16, k16);

    scores_vt_gemm<<<1856, 256, 0, stream>>>(
        q16, k16, x16, w16, sp16, vt16, rsum, 0.03608439182435161f);

    pv_gemm<<<768, 256, 0, stream>>>(sp16, vt16, rsum, out);
}

// Round 11
// 178.037 us; speedup vs baseline: 1.0957x; 1.0357x over previous
//
#include <hip/hip_runtime.h>
#include <hip/hip_bf16.h>
#include <cstdint>
#include <cstddef>

// B=4, S=2048, D=768 single-head causal attention, fp32 I/O.
// Round 16: sv grid packed to exactly 2 residency waves. R10 measured the
// swizzled gemm64 sv at 49.9 us with 1856 uniform blocks at 3 blocks/CU (768
// resident): makespan ~3T (last wave only 320/768 full) for 2.42T of work.
// New grid: 1536 blocks; blocks 0..319 do TWO tiles (own + 1536+b), launched
// first (LPT: hardware dispatches blockIdx ascending, singles backfill) ->
// makespan ~2T ~= 34 us. LDS-safety: gemm64's final in-loop __syncthreads
// (drains vmcnt(0)) is after the last LDS read and the epilogue is
// register/global-only, so tile2's restage can't race tile1's reads. XCD
// tile-swizzle dropped for sv (launch order must equal blockIdx order for
// LPT; swizzle was never A/B-proven here). qk, pv, cvt, both GEMM cores
// byte-identical to R10 (sv conflicts 0, 467 TF; qk 611 TF; pv ~570 TF).

typedef __attribute__((ext_vector_type(8))) short short8;   // 8 x bf16
typedef __attribute__((ext_vector_type(4))) float f32x4;    // MFMA C/D

#define GPTR(p) (const __attribute__((address_space(1))) void*)(p)
#define LPTR(p) (__attribute__((address_space(3))) void*)(p)

constexpr int CB = 4, CS = 2048, CD = 768;
constexpr int CBS = CB * CS;            // 8192

// T1: XCD-aware bijective swizzle (requires nwg % 8 == 0). Only for grids
// with uniform block durations (R7 lesson: never on LPT grids).
__device__ __forceinline__ int xcd_swz(int bid, int nwg) {
    return (bid & 7) * (nwg >> 3) + (bid >> 3);
}

__device__ inline unsigned short f2bf_bits(float v) {
    __hip_bfloat16 h = __float2bfloat16(v);
    unsigned short u;
    __builtin_memcpy(&u, &h, 2);
    return u;
}

__device__ inline ushort4 cvt4(float4 f) {
    ushort4 u;
    u.x = f2bf_bits(f.x); u.y = f2bf_bits(f.y);
    u.z = f2bf_bits(f.z); u.w = f2bf_bits(f.w);
    return u;
}

template <int MI>
__device__ __forceinline__ void zero_acc(f32x4 (&acc)[MI][4]) {
#pragma unroll
    for (int i = 0; i < MI; ++i)
#pragma unroll
        for (int j = 0; j < 4; ++j)
            acc[i][j] = f32x4{0.f, 0.f, 0.f, 0.f};
}

// ---------------------------------------------------------------------------
// single cast dispatch: x -> x16, Wq|Wk|Wv -> w16, and zero rowsum.
// ---------------------------------------------------------------------------
__global__ __launch_bounds__(256) void cvt_all(
    const float4* __restrict__ x,  const float4* __restrict__ wq,
    const float4* __restrict__ wk, const float4* __restrict__ wv,
    ushort4* __restrict__ x16, ushort4* __restrict__ w16,
    float4* __restrict__ rsum4)
{
    constexpr int NX = CBS * CD / 4;        // 1572864
    constexpr int NW = CD * CD / 4;         // 147456
    constexpr int NT = NX + 3 * NW;         // 2015232 (divisible by 256)
    const int i = blockIdx.x * 256 + threadIdx.x;
    if (i < NX) {
        x16[i] = cvt4(x[i]);
    } else if (i < NT) {
        const int j = i - NX;
        if (j < NW)            w16[j] = cvt4(wq[j]);
        else if (j < 2 * NW)   w16[j] = cvt4(wk[j - NW]);
        else                   w16[j] = cvt4(wv[j - 2 * NW]);
    } else {
        const int j = i - NT;               // 0..2047 : zero rowsum (8192 f32)
        rsum4[j] = float4{0.f, 0.f, 0.f, 0.f};
    }
}

// ---------------------------------------------------------------------------
// 2-phase GEMM core (qk): acc[MI][4] += A[m,k]*B[n,k], BM x 128 tile, BK=32
// double-buffered prefetch.  (unchanged)
// ---------------------------------------------------------------------------
template <int BM>
__device__ __forceinline__ void gemm_core(
    const __hip_bfloat16* __restrict__ A,
    const __hip_bfloat16* __restrict__ B,
    __hip_bfloat16* As, __hip_bfloat16* Bs,
    int m0, int n0, int K, int kend,
    f32x4 (&acc)[BM / 32][4])
{
    constexpr int AC = BM / 16;
    constexpr int SC = AC + 8;
    constexpr int MI = BM / 32;

    const int t  = threadIdx.x;
    const int w  = t >> 6;
    const int l  = t & 63;
    const int lq = l >> 4;
    const int lm = l & 15;
    const int wm = (w >> 1) * (BM / 2);
    const int wn = (w & 1) * 64;

    const int srow = l >> 2;
    const int scol = (l & 3) * 8;

    auto stage = [&](int buf, int k0) {
#pragma unroll
        for (int ci = 0; ci < SC / 4; ++ci) {
            const int c = ci * 4 + w;
            if (c < AC) {
                __builtin_amdgcn_global_load_lds(
                    GPTR(A + (size_t)(m0 + c * 16 + srow) * K + k0 + scol),
                    LPTR(&As[buf * BM * 32 + c * 512]), 16, 0, 0);
            } else {
                const int c2 = c - AC;
                __builtin_amdgcn_global_load_lds(
                    GPTR(B + (size_t)(n0 + c2 * 16 + srow) * K + k0 + scol),
                    LPTR(&Bs[buf * 128 * 32 + c2 * 512]), 16, 0, 0);
            }
        }
    };

    stage(0, 0);
    asm volatile("s_waitcnt vmcnt(0)" ::: "memory");
    __syncthreads();

    int cur = 0;
    for (int k0 = 0; k0 < kend; k0 += 32) {
        if (k0 + 32 < kend)
            stage(cur ^ 1, k0 + 32);

        short8 af[MI], bf[4];
#pragma unroll
        for (int i = 0; i < MI; ++i)
            af[i] = *(const short8*)&As[cur * BM * 32 + (wm + i * 16 + lm) * 32 + lq * 8];
#pragma unroll
        for (int j = 0; j < 4; ++j)
            bf[j] = *(const short8*)&Bs[cur * 128 * 32 + (wn + j * 16 + lm) * 32 + lq * 8];

#pragma unroll
        for (int i = 0; i < MI; ++i)
#pragma unroll
            for (int j = 0; j < 4; ++j)
                acc[i][j] = __builtin_amdgcn_mfma_f32_16x16x32_bf16(
                    af[i], bf[j], acc[i][j], 0, 0, 0);

        __syncthreads();
        cur ^= 1;
    }
}

// ---------------------------------------------------------------------------
// Q/K projections, 128x128 tiles, 768 blocks (Q: 0..383, K: 384..767).
// All 768 blocks resident at once (5 blocks/CU capacity) -> order-insensitive.
// ---------------------------------------------------------------------------
__global__ __launch_bounds__(256) void qk_gemm(
    const __hip_bfloat16* __restrict__ x16,
    const __hip_bfloat16* __restrict__ w16,
    __hip_bfloat16* __restrict__ q16,
    __hip_bfloat16* __restrict__ k16)
{
    __shared__ __align__(16) __hip_bfloat16 As[2 * 128 * 32];   // 16 KB
    __shared__ __align__(16) __hip_bfloat16 Bs[2 * 128 * 32];   // 16 KB

    const int id   = xcd_swz(blockIdx.x, 768);   // 0..767
    const int proj = id / 384;            // 0=Q, 1=K
    const int r    = id % 384;
    const int n0   = (r % 6) * 128;
    const int m0   = (r / 6) * 128;

    f32x4 acc[4][4];
    zero_acc<4>(acc);
    gemm_core<128>(x16, w16 + (size_t)proj * CD * CD, As, Bs, m0, n0, CD, CD, acc);

    __hip_bfloat16* C = proj ? k16 : q16;
    const int t  = threadIdx.x;
    const int w  = t >> 6;
    const int l  = t & 63;
    const int lq = l >> 4;
    const int lm = l & 15;
    const int wm = (w >> 1) * 64;
    const int wn = (w & 1) * 64;
#pragma unroll
    for (int i = 0; i < 4; ++i)
#pragma unroll
        for (int j = 0; j < 4; ++j) {
            const int n = n0 + wn + j * 16 + lm;
#pragma unroll
            for (int r2 = 0; r2 < 4; ++r2) {
                const int m = m0 + wm + i * 16 + lq * 4 + r2;
                C[(size_t)m * CD + n] = __float2bfloat16(acc[i][j][r2]);
            }
        }
}

// ---------------------------------------------------------------------------
// gemm64 core (SWIZZLED, R10-verified 0 conflicts): 64x128 tile, BK=64,
// double-buffered prefetch, one barrier+drain per 64 K-elements.
// LDS: As[buf][row][gran] rows of 64 bf16 (128 B); LDS(row,g) holds global
// granule g^(row&7). Stage: linear wave-uniform dest + per-lane pre-swizzled
// global source. Reads: c0=(lq^(lm&7))*8, c1=c0^32. 48 KB total.
// ---------------------------------------------------------------------------
__device__ __forceinline__ void gemm64_core(
    const __hip_bfloat16* __restrict__ A,
    const __hip_bfloat16* __restrict__ B,
    __hip_bfloat16* As, __hip_bfloat16* Bs,
    int m0, int n0, int K, int kend,
    f32x4 (&acc)[2][4])
{
    const int t  = threadIdx.x;
    const int w  = t >> 6;
    const int l  = t & 63;
    const int lq = l >> 4;
    const int lm = l & 15;
    const int wm = (w >> 1) * 32;
    const int wn = (w & 1) * 64;

    const int lrow8 = l >> 3;         // row within an 8-row staging call
    const int gl    = l & 7;          // LDS granule this lane fills
    const int c0    = (lq ^ (lm & 7)) * 8;   // swizzled read granule, slab 0
    const int c1    = c0 ^ 32;               // slab 1

    auto stage = [&](int buf, int k0) {
#pragma unroll
        for (int ci = 0; ci < 6; ++ci) {
            const int c = ci * 4 + w;         // wave-uniform call id, 0..23
            if (c < 8) {                      // A: 8 calls x 8 rows
                const int r0  = c * 8;
                const int row = r0 + lrow8;
                const int gg  = gl ^ (row & 7);
                __builtin_amdgcn_global_load_lds(
                    GPTR(A + (size_t)(m0 + row) * K + k0 + gg * 8),
                    LPTR(&As[buf * 4096 + r0 * 64]), 16, 0, 0);
            } else {                          // B: 16 calls x 8 rows
                const int cb  = c - 8;
                const int r0  = cb * 8;
                const int row = r0 + lrow8;
                const int gg  = gl ^ (row & 7);
                __builtin_amdgcn_global_load_lds(
                    GPTR(B + (size_t)(n0 + row) * K + k0 + gg * 8),
                    LPTR(&Bs[buf * 8192 + r0 * 64]), 16, 0, 0);
            }
        }
    };

    stage(0, 0);
    asm volatile("s_waitcnt vmcnt(0)" ::: "memory");
    __syncthreads();

    int cur = 0;
    for (int k0 = 0; k0 < kend; k0 += 64) {
        if (k0 + 64 < kend)
            stage(cur ^ 1, k0 + 64);        // prefetch overlaps the MFMAs below

#pragma unroll
        for (int kk = 0; kk < 2; ++kk) {
            const int cg = kk ? c1 : c0;
            short8 af[2], bf[4];
#pragma unroll
            for (int i = 0; i < 2; ++i)
                af[i] = *(const short8*)&As[cur * 4096 + (wm + i * 16 + lm) * 64 + cg];
#pragma unroll
            for (int j = 0; j < 4; ++j)
                bf[j] = *(const short8*)&Bs[cur * 8192 + (wn + j * 16 + lm) * 64 + cg];
#pragma unroll
            for (int i = 0; i < 2; ++i)
#pragma unroll
                for (int j = 0; j < 4; ++j)
                    acc[i][j] = __builtin_amdgcn_mfma_f32_16x16x32_bf16(
                        af[i], bf[j], acc[i][j], 0, 0, 0);
        }

        __syncthreads();
        cur ^= 1;
    }
}

// ---------------------------------------------------------------------------
// One sv tile: id < 1088 -> compact-causal score tile (E=exp, rowsum atomic);
// id >= 1088 -> V^T projection tile. All tiles K=768 (uniform duration).
// ---------------------------------------------------------------------------
__device__ __forceinline__ void sv_tile(
    int id,
    const __hip_bfloat16* __restrict__ q16,
    const __hip_bfloat16* __restrict__ k16,
    const __hip_bfloat16* __restrict__ x16,
    const __hip_bfloat16* __restrict__ w16,
    __hip_bfloat16* __restrict__ sp16,
    __hip_bfloat16* __restrict__ vt16,
    float* __restrict__ rowsum, float scale,
    __hip_bfloat16* As, __hip_bfloat16* Bs)
{
    const bool is_sc = (id < 1088);
    const __hip_bfloat16 *A, *B;
    int m0, n0, b;

    if (is_sc) {
        b = id & 3;
        const int tt = id >> 2;           // 0..271
        int s = (int)sqrtf((float)tt);
        while ((s + 1) * (s + 1) <= tt) ++s;
        while (s * s > tt) --s;
        int mi, nj;
        if (tt < s * (s + 1)) { mi = 2 * s - 1; nj = tt - s * s; }
        else                  { mi = 2 * s;     nj = tt - s * (s + 1); }
        m0 = mi * 64;
        n0 = nj * 128;
        A = q16 + (size_t)b * CS * CD;
        B = k16 + (size_t)b * CS * CD;
    } else {
        int r = id - 1088;                // 0..767
        b = r / 192; r %= 192;
        m0 = (r / 16) * 64;               // d-tile (12 of 64)
        n0 = (r % 16) * 128;              // s-tile (16 of 128)
        A = w16 + (size_t)2 * CD * CD;    // Wv
        B = x16 + (size_t)b * CS * CD;
    }

    f32x4 acc[2][4];
    zero_acc<2>(acc);
    gemm64_core(A, B, As, Bs, m0, n0, CD, CD, acc);

    const int t  = threadIdx.x;
    const int w  = t >> 6;
    const int l  = t & 63;
    const int lq = l >> 4;
    const int lm = l & 15;
    const int wm = (w >> 1) * 32;
    const int wn = (w & 1) * 64;

    if (is_sc) {
        __hip_bfloat16* C = sp16 + (size_t)b * CS * CS;
        float* rs = rowsum + (size_t)b * CS;
#pragma unroll
        for (int i = 0; i < 2; ++i) {
            float psum[4] = {0.f, 0.f, 0.f, 0.f};
#pragma unroll
            for (int j = 0; j < 4; ++j) {
                const int n = n0 + wn + j * 16 + lm;
#pragma unroll
                for (int r2 = 0; r2 < 4; ++r2) {
                    const int m = m0 + wm + i * 16 + lq * 4 + r2;
                    float e = (n <= m) ? __expf(acc[i][j][r2] * scale) : 0.f;
                    C[(size_t)m * CS + n] = __float2bfloat16(e);
                    psum[r2] += e;
                }
            }
#pragma unroll
            for (int r2 = 0; r2 < 4; ++r2) {
#pragma unroll
                for (int off = 1; off < 16; off <<= 1)
                    psum[r2] += __shfl_xor(psum[r2], off);
                if (lm == 0) {
                    const int m = m0 + wm + i * 16 + lq * 4 + r2;
                    atomicAdd(&rs[m], psum[r2]);
                }
            }
        }
    } else {
        __hip_bfloat16* C = vt16 + (size_t)b * CD * CS;
#pragma unroll
        for (int i = 0; i < 2; ++i)
#pragma unroll
            for (int j = 0; j < 4; ++j) {
                const int n = n0 + wn + j * 16 + lm;
#pragma unroll
                for (int r2 = 0; r2 < 4; ++r2) {
                    const int m = m0 + wm + i * 16 + lq * 4 + r2;
                    C[(size_t)m * CS + n] = __float2bfloat16(acc[i][j][r2]);
                }
            }
    }
}

// ---------------------------------------------------------------------------
// sv dispatch: 1536 blocks = 2 residency waves at 3 blocks/CU. Blocks 0..319
// (launched first) each do two tiles (b and 1536+b) -> LPT packing, makespan
// ~2T instead of 3T. Safe back-to-back core calls: final in-loop barrier
// drains vmcnt(0) after the last LDS read; epilogue is register/global only.
// ---------------------------------------------------------------------------
__global__ __launch_bounds__(256) void scores_vt_gemm(
    const __hip_bfloat16* __restrict__ q16,
    const __hip_bfloat16* __restrict__ k16,
    const __hip_bfloat16* __restrict__ x16,
    const __hip_bfloat16* __restrict__ w16,
    __hip_bfloat16* __restrict__ sp16,
    __hip_bfloat16* __restrict__ vt16,
    float* __restrict__ rowsum,
    float scale)
{
    __shared__ __align__(16) __hip_bfloat16 As[2 * 4096];   // 16 KB
    __shared__ __align__(16) __hip_bfloat16 Bs[2 * 8192];   // 32 KB

    const int b = blockIdx.x;           // 0..1535, ascending launch order
    sv_tile(b, q16, k16, x16, w16, sp16, vt16, rowsum, scale, As, Bs);
    if (b < 320)
        sv_tile(1536 + b, q16, k16, x16, w16, sp16, vt16, rowsum, scale, As, Bs);
}

// ---------------------------------------------------------------------------
// out[b] = (E[b] @ Vt[b]^T) / rowsum, 64x128 tiles, kend = m0+64,
// heavy-first (LPT) ordering, no XCD swizzle (R7 lesson).
// ---------------------------------------------------------------------------
__global__ __launch_bounds__(256) void pv_gemm(
    const __hip_bfloat16* __restrict__ sp16,
    const __hip_bfloat16* __restrict__ vt16,
    const float* __restrict__ rowsum,
    float* __restrict__ out)
{
    const int id   = blockIdx.x;        // 0..767
    const int mrev = id / 24;
    int r          = id % 24;
    const int b    = r / 6;
    const int n0   = (r % 6) * 128;
    const int mi   = 31 - mrev;         // heavy (large kend) first
    const int m0   = mi * 64;
    const int kend = m0 + 64;

    __shared__ __align__(16) __hip_bfloat16 As[2 * 4096];   // 16 KB
    __shared__ __align__(16) __hip_bfloat16 Bs[2 * 8192];   // 32 KB

    const __hip_bfloat16* A = sp16 + (size_t)b * CS * CS;
    const __hip_bfloat16* B = vt16 + (size_t)b * CD * CS;
    float* Co = out + (size_t)b * CS * CD;
    const float* rs = rowsum + (size_t)b * CS;

    f32x4 acc[2][4];
    zero_acc<2>(acc);
    gemm64_core(A, B, As, Bs, m0, n0, CS, kend, acc);

    const int t  = threadIdx.x;
    const int w  = t >> 6;
    const int l  = t & 63;
    const int lq = l >> 4;
    const int lm = l & 15;
    const int wm = (w >> 1) * 32;
    const int wn = (w & 1) * 64;

#pragma unroll
    for (int i = 0; i < 2; ++i) {
        float inv[4];
#pragma unroll
        for (int r2 = 0; r2 < 4; ++r2)
            inv[r2] = 1.0f / rs[m0 + wm + i * 16 + lq * 4 + r2];
#pragma unroll
        for (int j = 0; j < 4; ++j) {
            const int n = n0 + wn + j * 16 + lm;
#pragma unroll
            for (int r2 = 0; r2 < 4; ++r2) {
                const int m = m0 + wm + i * 16 + lq * 4 + r2;
                Co[(size_t)m * CD + n] = acc[i][j][r2] * inv[r2];
            }
        }
    }
}

// ---------------------------------------------------------------------------
// Launch
// ---------------------------------------------------------------------------
extern "C" void kernel_launch(void* const* d_in, const int* in_sizes, int n_in,
                              void* d_out, int out_size, void* d_ws, size_t ws_size,
                              hipStream_t stream)
{
    const float* x  = (const float*)d_in[0];
    const float* Wq = (const float*)d_in[1];
    const float* Wk = (const float*)d_in[2];
    const float* Wv = (const float*)d_in[3];
    float* out = (float*)d_out;

    char* ws = (char*)d_ws;
    size_t off = 0;
    auto alloc = [&](size_t bytes) { char* p = ws + off; off += bytes; return p; };

    __hip_bfloat16* x16  = (__hip_bfloat16*)alloc((size_t)CBS * CD * 2);
    __hip_bfloat16* q16  = (__hip_bfloat16*)alloc((size_t)CBS * CD * 2);
    __hip_bfloat16* k16  = (__hip_bfloat16*)alloc((size_t)CBS * CD * 2);
    __hip_bfloat16* vt16 = (__hip_bfloat16*)alloc((size_t)CBS * CD * 2);   // [B][D][S]
    __hip_bfloat16* sp16 = (__hip_bfloat16*)alloc((size_t)CB * CS * CS * 2);
    __hip_bfloat16* w16  = (__hip_bfloat16*)alloc((size_t)3 * CD * CD * 2);
    float*          rsum = (float*)alloc((size_t)CB * CS * sizeof(float));

    constexpr int NCVT_BLK = (CBS * CD + 3 * CD * CD) / 4 / 256 + 8;
    cvt_all<<<NCVT_BLK, 256, 0, stream>>>(
        (const float4*)x, (const float4*)Wq, (const float4*)Wk, (const float4*)Wv,
        (ushort4*)x16, (ushort4*)w16, (float4*)rsum);

    qk_gemm<<<768, 256, 0, stream>>>(x16, w16, q16, k16);

    scores_vt_gemm<<<1536, 256, 0, stream>>>(
        q16, k16, x16, w16, sp16, vt16, rsum, 0.03608439182435161f);

    pv_gemm<<<768, 256, 0, stream>>>(sp16, vt16, rsum, out);
}

// Round 12
// 170.948 us; speedup vs baseline: 1.1411x; 1.0415x over previous
//
#include <hip/hip_runtime.h>
#include <hip/hip_bf16.h>
#include <cstdint>
#include <cstddef>

// B=4, S=2048, D=768 single-head causal attention, fp32 I/O.
// Round 17: qk gets the bank-conflict fix (last counter-backed lever).
// Its BK=32 core had the original 8-way ds_read_b128 conflict (3.54M
// conflict-cycles measured R0/R1): 64B rows -> bank = (lm&1)*16 + lq*4.
// Fix INSIDE the 64B-row geometry (no LDS/occupancy change): granule-XOR
// swizzle with key (row>>1)&3 (row bit 0 already splits banks via the x16
// term). Staging keeps linear wave-uniform LDS dest, pre-swizzles the
// per-lane GLOBAL granule (rule 21): gg = (l&3)^((srow>>1)&3); reads use
// cr = lq^((lm>>1)&3). Bank audit: fixed (parity,lq) lanes spread over all
// 4 bank-groups, 2 lanes each = 2-way = free (m136). Involution: LDS(row,g)
// holds global g^key(row); read at lq^key returns global lq. Key uses row
// bits 1-2 only -> invariant to 16-row-aligned chunk offsets.
// Everything else byte-identical to R11 (sv 2-wave packed + swizzled gemm64,
// pv gemm64 LPT, cvt). R11 state: all kernels < 42 us; top-5 = harness
// fillBuffers (268 MB re-poison, not controllable).

typedef __attribute__((ext_vector_type(8))) short short8;   // 8 x bf16
typedef __attribute__((ext_vector_type(4))) float f32x4;    // MFMA C/D

#define GPTR(p) (const __attribute__((address_space(1))) void*)(p)
#define LPTR(p) (__attribute__((address_space(3))) void*)(p)

constexpr int CB = 4, CS = 2048, CD = 768;
constexpr int CBS = CB * CS;            // 8192

// T1: XCD-aware bijective swizzle (requires nwg % 8 == 0). Only for grids
// with uniform block durations (R7 lesson: never on LPT grids).
__device__ __forceinline__ int xcd_swz(int bid, int nwg) {
    return (bid & 7) * (nwg >> 3) + (bid >> 3);
}

__device__ inline unsigned short f2bf_bits(float v) {
    __hip_bfloat16 h = __float2bfloat16(v);
    unsigned short u;
    __builtin_memcpy(&u, &h, 2);
    return u;
}

__device__ inline ushort4 cvt4(float4 f) {
    ushort4 u;
    u.x = f2bf_bits(f.x); u.y = f2bf_bits(f.y);
    u.z = f2bf_bits(f.z); u.w = f2bf_bits(f.w);
    return u;
}

template <int MI>
__device__ __forceinline__ void zero_acc(f32x4 (&acc)[MI][4]) {
#pragma unroll
    for (int i = 0; i < MI; ++i)
#pragma unroll
        for (int j = 0; j < 4; ++j)
            acc[i][j] = f32x4{0.f, 0.f, 0.f, 0.f};
}

// ---------------------------------------------------------------------------
// single cast dispatch: x -> x16, Wq|Wk|Wv -> w16, and zero rowsum.
// ---------------------------------------------------------------------------
__global__ __launch_bounds__(256) void cvt_all(
    const float4* __restrict__ x,  const float4* __restrict__ wq,
    const float4* __restrict__ wk, const float4* __restrict__ wv,
    ushort4* __restrict__ x16, ushort4* __restrict__ w16,
    float4* __restrict__ rsum4)
{
    constexpr int NX = CBS * CD / 4;        // 1572864
    constexpr int NW = CD * CD / 4;         // 147456
    constexpr int NT = NX + 3 * NW;         // 2015232 (divisible by 256)
    const int i = blockIdx.x * 256 + threadIdx.x;
    if (i < NX) {
        x16[i] = cvt4(x[i]);
    } else if (i < NT) {
        const int j = i - NX;
        if (j < NW)            w16[j] = cvt4(wq[j]);
        else if (j < 2 * NW)   w16[j] = cvt4(wk[j - NW]);
        else                   w16[j] = cvt4(wv[j - 2 * NW]);
    } else {
        const int j = i - NT;               // 0..2047 : zero rowsum (8192 f32)
        rsum4[j] = float4{0.f, 0.f, 0.f, 0.f};
    }
}

// ---------------------------------------------------------------------------
// 2-phase GEMM core (qk): acc[MI][4] += A[m,k]*B[n,k], BM x 128 tile, BK=32
// double-buffered prefetch, NOW with granule-XOR bank-conflict swizzle.
// LDS(16-row chunk, row r, granule g) holds global granule g^((r>>1)&3) of
// that row's 32-k slice. Stage: linear dest + pre-swizzled global source.
// Read granule: lq^((lm>>1)&3).
// ---------------------------------------------------------------------------
template <int BM>
__device__ __forceinline__ void gemm_core(
    const __hip_bfloat16* __restrict__ A,
    const __hip_bfloat16* __restrict__ B,
    __hip_bfloat16* As, __hip_bfloat16* Bs,
    int m0, int n0, int K, int kend,
    f32x4 (&acc)[BM / 32][4])
{
    constexpr int AC = BM / 16;
    constexpr int SC = AC + 8;
    constexpr int MI = BM / 32;

    const int t  = threadIdx.x;
    const int w  = t >> 6;
    const int l  = t & 63;
    const int lq = l >> 4;
    const int lm = l & 15;
    const int wm = (w >> 1) * (BM / 2);
    const int wn = (w & 1) * 64;

    const int srow = l >> 2;                        // lane row within chunk
    const int scol = ((l & 3) ^ ((srow >> 1) & 3)) * 8;   // pre-swizzled global granule
    const int cr   = (lq ^ ((lm >> 1) & 3)) * 8;    // swizzled read granule

    auto stage = [&](int buf, int k0) {
#pragma unroll
        for (int ci = 0; ci < SC / 4; ++ci) {
            const int c = ci * 4 + w;
            if (c < AC) {
                __builtin_amdgcn_global_load_lds(
                    GPTR(A + (size_t)(m0 + c * 16 + srow) * K + k0 + scol),
                    LPTR(&As[buf * BM * 32 + c * 512]), 16, 0, 0);
            } else {
                const int c2 = c - AC;
                __builtin_amdgcn_global_load_lds(
                    GPTR(B + (size_t)(n0 + c2 * 16 + srow) * K + k0 + scol),
                    LPTR(&Bs[buf * 128 * 32 + c2 * 512]), 16, 0, 0);
            }
        }
    };

    stage(0, 0);
    asm volatile("s_waitcnt vmcnt(0)" ::: "memory");
    __syncthreads();

    int cur = 0;
    for (int k0 = 0; k0 < kend; k0 += 32) {
        if (k0 + 32 < kend)
            stage(cur ^ 1, k0 + 32);

        short8 af[MI], bf[4];
#pragma unroll
        for (int i = 0; i < MI; ++i)
            af[i] = *(const short8*)&As[cur * BM * 32 + (wm + i * 16 + lm) * 32 + cr];
#pragma unroll
        for (int j = 0; j < 4; ++j)
            bf[j] = *(const short8*)&Bs[cur * 128 * 32 + (wn + j * 16 + lm) * 32 + cr];

#pragma unroll
        for (int i = 0; i < MI; ++i)
#pragma unroll
            for (int j = 0; j < 4; ++j)
                acc[i][j] = __builtin_amdgcn_mfma_f32_16x16x32_bf16(
                    af[i], bf[j], acc[i][j], 0, 0, 0);

        __syncthreads();
        cur ^= 1;
    }
}

// ---------------------------------------------------------------------------
// Q/K projections, 128x128 tiles, 768 blocks (Q: 0..383, K: 384..767).
// All 768 blocks resident at once -> order-insensitive.
// ---------------------------------------------------------------------------
__global__ __launch_bounds__(256) void qk_gemm(
    const __hip_bfloat16* __restrict__ x16,
    const __hip_bfloat16* __restrict__ w16,
    __hip_bfloat16* __restrict__ q16,
    __hip_bfloat16* __restrict__ k16)
{
    __shared__ __align__(16) __hip_bfloat16 As[2 * 128 * 32];   // 16 KB
    __shared__ __align__(16) __hip_bfloat16 Bs[2 * 128 * 32];   // 16 KB

    const int id   = xcd_swz(blockIdx.x, 768);   // 0..767
    const int proj = id / 384;            // 0=Q, 1=K
    const int r    = id % 384;
    const int n0   = (r % 6) * 128;
    const int m0   = (r / 6) * 128;

    f32x4 acc[4][4];
    zero_acc<4>(acc);
    gemm_core<128>(x16, w16 + (size_t)proj * CD * CD, As, Bs, m0, n0, CD, CD, acc);

    __hip_bfloat16* C = proj ? k16 : q16;
    const int t  = threadIdx.x;
    const int w  = t >> 6;
    const int l  = t & 63;
    const int lq = l >> 4;
    const int lm = l & 15;
    const int wm = (w >> 1) * 64;
    const int wn = (w & 1) * 64;
#pragma unroll
    for (int i = 0; i < 4; ++i)
#pragma unroll
        for (int j = 0; j < 4; ++j) {
            const int n = n0 + wn + j * 16 + lm;
#pragma unroll
            for (int r2 = 0; r2 < 4; ++r2) {
                const int m = m0 + wm + i * 16 + lq * 4 + r2;
                C[(size_t)m * CD + n] = __float2bfloat16(acc[i][j][r2]);
            }
        }
}

// ---------------------------------------------------------------------------
// gemm64 core (SWIZZLED, R10-verified 0 conflicts): 64x128 tile, BK=64,
// double-buffered prefetch, one barrier+drain per 64 K-elements.
// ---------------------------------------------------------------------------
__device__ __forceinline__ void gemm64_core(
    const __hip_bfloat16* __restrict__ A,
    const __hip_bfloat16* __restrict__ B,
    __hip_bfloat16* As, __hip_bfloat16* Bs,
    int m0, int n0, int K, int kend,
    f32x4 (&acc)[2][4])
{
    const int t  = threadIdx.x;
    const int w  = t >> 6;
    const int l  = t & 63;
    const int lq = l >> 4;
    const int lm = l & 15;
    const int wm = (w >> 1) * 32;
    const int wn = (w & 1) * 64;

    const int lrow8 = l >> 3;         // row within an 8-row staging call
    const int gl    = l & 7;          // LDS granule this lane fills
    const int c0    = (lq ^ (lm & 7)) * 8;   // swizzled read granule, slab 0
    const int c1    = c0 ^ 32;               // slab 1

    auto stage = [&](int buf, int k0) {
#pragma unroll
        for (int ci = 0; ci < 6; ++ci) {
            const int c = ci * 4 + w;         // wave-uniform call id, 0..23
            if (c < 8) {                      // A: 8 calls x 8 rows
                const int r0  = c * 8;
                const int row = r0 + lrow8;
                const int gg  = gl ^ (row & 7);
                __builtin_amdgcn_global_load_lds(
                    GPTR(A + (size_t)(m0 + row) * K + k0 + gg * 8),
                    LPTR(&As[buf * 4096 + r0 * 64]), 16, 0, 0);
            } else {                          // B: 16 calls x 8 rows
                const int cb  = c - 8;
                const int r0  = cb * 8;
                const int row = r0 + lrow8;
                const int gg  = gl ^ (row & 7);
                __builtin_amdgcn_global_load_lds(
                    GPTR(B + (size_t)(n0 + row) * K + k0 + gg * 8),
                    LPTR(&Bs[buf * 8192 + r0 * 64]), 16, 0, 0);
            }
        }
    };

    stage(0, 0);
    asm volatile("s_waitcnt vmcnt(0)" ::: "memory");
    __syncthreads();

    int cur = 0;
    for (int k0 = 0; k0 < kend; k0 += 64) {
        if (k0 + 64 < kend)
            stage(cur ^ 1, k0 + 64);        // prefetch overlaps the MFMAs below

#pragma unroll
        for (int kk = 0; kk < 2; ++kk) {
            const int cg = kk ? c1 : c0;
            short8 af[2], bf[4];
#pragma unroll
            for (int i = 0; i < 2; ++i)
                af[i] = *(const short8*)&As[cur * 4096 + (wm + i * 16 + lm) * 64 + cg];
#pragma unroll
            for (int j = 0; j < 4; ++j)
                bf[j] = *(const short8*)&Bs[cur * 8192 + (wn + j * 16 + lm) * 64 + cg];
#pragma unroll
            for (int i = 0; i < 2; ++i)
#pragma unroll
                for (int j = 0; j < 4; ++j)
                    acc[i][j] = __builtin_amdgcn_mfma_f32_16x16x32_bf16(
                        af[i], bf[j], acc[i][j], 0, 0, 0);
        }

        __syncthreads();
        cur ^= 1;
    }
}

// ---------------------------------------------------------------------------
// One sv tile: id < 1088 -> compact-causal score tile (E=exp, rowsum atomic);
// id >= 1088 -> V^T projection tile. All tiles K=768 (uniform duration).
// ---------------------------------------------------------------------------
__device__ __forceinline__ void sv_tile(
    int id,
    const __hip_bfloat16* __restrict__ q16,
    const __hip_bfloat16* __restrict__ k16,
    const __hip_bfloat16* __restrict__ x16,
    const __hip_bfloat16* __restrict__ w16,
    __hip_bfloat16* __restrict__ sp16,
    __hip_bfloat16* __restrict__ vt16,
    float* __restrict__ rowsum, float scale,
    __hip_bfloat16* As, __hip_bfloat16* Bs)
{
    const bool is_sc = (id < 1088);
    const __hip_bfloat16 *A, *B;
    int m0, n0, b;

    if (is_sc) {
        b = id & 3;
        const int tt = id >> 2;           // 0..271
        int s = (int)sqrtf((float)tt);
        while ((s + 1) * (s + 1) <= tt) ++s;
        while (s * s > tt) --s;
        int mi, nj;
        if (tt < s * (s + 1)) { mi = 2 * s - 1; nj = tt - s * s; }
        else                  { mi = 2 * s;     nj = tt - s * (s + 1); }
        m0 = mi * 64;
        n0 = nj * 128;
        A = q16 + (size_t)b * CS * CD;
        B = k16 + (size_t)b * CS * CD;
    } else {
        int r = id - 1088;                // 0..767
        b = r / 192; r %= 192;
        m0 = (r / 16) * 64;               // d-tile (12 of 64)
        n0 = (r % 16) * 128;              // s-tile (16 of 128)
        A = w16 + (size_t)2 * CD * CD;    // Wv
        B = x16 + (size_t)b * CS * CD;
    }

    f32x4 acc[2][4];
    zero_acc<2>(acc);
    gemm64_core(A, B, As, Bs, m0, n0, CD, CD, acc);

    const int t  = threadIdx.x;
    const int w  = t >> 6;
    const int l  = t & 63;
    const int lq = l >> 4;
    const int lm = l & 15;
    const int wm = (w >> 1) * 32;
    const int wn = (w & 1) * 64;

    if (is_sc) {
        __hip_bfloat16* C = sp16 + (size_t)b * CS * CS;
        float* rs = rowsum + (size_t)b * CS;
#pragma unroll
        for (int i = 0; i < 2; ++i) {
            float psum[4] = {0.f, 0.f, 0.f, 0.f};
#pragma unroll
            for (int j = 0; j < 4; ++j) {
                const int n = n0 + wn + j * 16 + lm;
#pragma unroll
                for (int r2 = 0; r2 < 4; ++r2) {
                    const int m = m0 + wm + i * 16 + lq * 4 + r2;
                    float e = (n <= m) ? __expf(acc[i][j][r2] * scale) : 0.f;
                    C[(size_t)m * CS + n] = __float2bfloat16(e);
                    psum[r2] += e;
                }
            }
#pragma unroll
            for (int r2 = 0; r2 < 4; ++r2) {
#pragma unroll
                for (int off = 1; off < 16; off <<= 1)
                    psum[r2] += __shfl_xor(psum[r2], off);
                if (lm == 0) {
                    const int m = m0 + wm + i * 16 + lq * 4 + r2;
                    atomicAdd(&rs[m], psum[r2]);
                }
            }
        }
    } else {
        __hip_bfloat16* C = vt16 + (size_t)b * CD * CS;
#pragma unroll
        for (int i = 0; i < 2; ++i)
#pragma unroll
            for (int j = 0; j < 4; ++j) {
                const int n = n0 + wn + j * 16 + lm;
#pragma unroll
                for (int r2 = 0; r2 < 4; ++r2) {
                    const int m = m0 + wm + i * 16 + lq * 4 + r2;
                    C[(size_t)m * CS + n] = __float2bfloat16(acc[i][j][r2]);
                }
            }
    }
}

// ---------------------------------------------------------------------------
// sv dispatch: 1536 blocks = 2 residency waves at 3 blocks/CU. Blocks 0..319
// (launched first) each do two tiles (b and 1536+b) -> LPT packing.
// ---------------------------------------------------------------------------
__global__ __launch_bounds__(256) void scores_vt_gemm(
    const __hip_bfloat16* __restrict__ q16,
    const __hip_bfloat16* __restrict__ k16,
    const __hip_bfloat16* __restrict__ x16,
    const __hip_bfloat16* __restrict__ w16,
    __hip_bfloat16* __restrict__ sp16,
    __hip_bfloat16* __restrict__ vt16,
    float* __restrict__ rowsum,
    float scale)
{
    __shared__ __align__(16) __hip_bfloat16 As[2 * 4096];   // 16 KB
    __shared__ __align__(16) __hip_bfloat16 Bs[2 * 8192];   // 32 KB

    const int b = blockIdx.x;           // 0..1535, ascending launch order
    sv_tile(b, q16, k16, x16, w16, sp16, vt16, rowsum, scale, As, Bs);
    if (b < 320)
        sv_tile(1536 + b, q16, k16, x16, w16, sp16, vt16, rowsum, scale, As, Bs);
}

// ---------------------------------------------------------------------------
// out[b] = (E[b] @ Vt[b]^T) / rowsum, 64x128 tiles, kend = m0+64,
// heavy-first (LPT) ordering, no XCD swizzle (R7 lesson).
// ---------------------------------------------------------------------------
__global__ __launch_bounds__(256) void pv_gemm(
    const __hip_bfloat16* __restrict__ sp16,
    const __hip_bfloat16* __restrict__ vt16,
    const float* __restrict__ rowsum,
    float* __restrict__ out)
{
    const int id   = blockIdx.x;        // 0..767
    const int mrev = id / 24;
    int r          = id % 24;
    const int b    = r / 6;
    const int n0   = (r % 6) * 128;
    const int mi   = 31 - mrev;         // heavy (large kend) first
    const int m0   = mi * 64;
    const int kend = m0 + 64;

    __shared__ __align__(16) __hip_bfloat16 As[2 * 4096];   // 16 KB
    __shared__ __align__(16) __hip_bfloat16 Bs[2 * 8192];   // 32 KB

    const __hip_bfloat16* A = sp16 + (size_t)b * CS * CS;
    const __hip_bfloat16* B = vt16 + (size_t)b * CD * CS;
    float* Co = out + (size_t)b * CS * CD;
    const float* rs = rowsum + (size_t)b * CS;

    f32x4 acc[2][4];
    zero_acc<2>(acc);
    gemm64_core(A, B, As, Bs, m0, n0, CS, kend, acc);

    const int t  = threadIdx.x;
    const int w  = t >> 6;
    const int l  = t & 63;
    const int lq = l >> 4;
    const int lm = l & 15;
    const int wm = (w >> 1) * 32;
    const int wn = (w & 1) * 64;

#pragma unroll
    for (int i = 0; i < 2; ++i) {
        float inv[4];
#pragma unroll
        for (int r2 = 0; r2 < 4; ++r2)
            inv[r2] = 1.0f / rs[m0 + wm + i * 16 + lq * 4 + r2];
#pragma unroll
        for (int j = 0; j < 4; ++j) {
            const int n = n0 + wn + j * 16 + lm;
#pragma unroll
            for (int r2 = 0; r2 < 4; ++r2) {
                const int m = m0 + wm + i * 16 + lq * 4 + r2;
                Co[(size_t)m * CD + n] = acc[i][j][r2] * inv[r2];
            }
        }
    }
}

// ---------------------------------------------------------------------------
// Launch
// ---------------------------------------------------------------------------
extern "C" void kernel_launch(void* const* d_in, const int* in_sizes, int n_in,
                              void* d_out, int out_size, void* d_ws, size_t ws_size,
                              hipStream_t stream)
{
    const float* x  = (const float*)d_in[0];
    const float* Wq = (const float*)d_in[1];
    const float* Wk = (const float*)d_in[2];
    const float* Wv = (const float*)d_in[3];
    float* out = (float*)d_out;

    char* ws = (char*)d_ws;
    size_t off = 0;
    auto alloc = [&](size_t bytes) { char* p = ws + off; off += bytes; return p; };

    __hip_bfloat16* x16  = (__hip_bfloat16*)alloc((size_t)CBS * CD * 2);
    __hip_bfloat16* q16  = (__hip_bfloat16*)alloc((size_t)CBS * CD * 2);
    __hip_bfloat16* k16  = (__hip_bfloat16*)alloc((size_t)CBS * CD * 2);
    __hip_bfloat16* vt16 = (__hip_bfloat16*)alloc((size_t)CBS * CD * 2);   // [B][D][S]
    __hip_bfloat16* sp16 = (__hip_bfloat16*)alloc((size_t)CB * CS * CS * 2);
    __hip_bfloat16* w16  = (__hip_bfloat16*)alloc((size_t)3 * CD * CD * 2);
    float*          rsum = (float*)alloc((size_t)CB * CS * sizeof(float));

    constexpr int NCVT_BLK = (CBS * CD + 3 * CD * CD) / 4 / 256 + 8;
    cvt_all<<<NCVT_BLK, 256, 0, stream>>>(
        (const float4*)x, (const float4*)Wq, (const float4*)Wk, (const float4*)Wv,
        (ushort4*)x16, (ushort4*)w16, (float4*)rsum);

    qk_gemm<<<768, 256, 0, stream>>>(x16, w16, q16, k16);

    scores_vt_gemm<<<1536, 256, 0, stream>>>(
        q16, k16, x16, w16, sp16, vt16, rsum, 0.03608439182435161f);

    pv_gemm<<<768, 256, 0, stream>>>(sp16, vt16, rsum, out);
}